// Round 16
// baseline (280.870 us; speedup 1.0000x reference)
//
#include <hip/hip_runtime.h>
#include <math.h>

#define DD 128

typedef __attribute__((ext_vector_type(8))) short short8;
typedef __attribute__((ext_vector_type(4))) float f32x4;

__device__ __forceinline__ unsigned short f2b(float f) {
    unsigned int x = __float_as_uint(f);
    return (unsigned short)((x + 0x7FFFu + ((x >> 16) & 1u)) >> 16);   // RNE bf16
}
__device__ __forceinline__ float b2f(unsigned short u) {
    return __uint_as_float(((unsigned int)u) << 16);
}

// ---------------- fused setup: blocks [0,192) transpose W->bf16, rest histogram dst ----------------
__global__ __launch_bounds__(256) void k_setup(const int* __restrict__ dst, int* __restrict__ cnt, int E,
                                               const float* __restrict__ W0, const float* __restrict__ W1,
                                               const float* __restrict__ W2, unsigned short* __restrict__ T0,
                                               unsigned short* __restrict__ T1, unsigned short* __restrict__ T2) {
    int bid = blockIdx.x;
    if (bid < 192) {
        int l = bid >> 6;
        const float* W = (l == 0) ? W0 : (l == 1) ? W1 : W2;
        unsigned short* WT = (l == 0) ? T0 : (l == 1) ? T1 : T2;
        int idx = (bid & 63) * 256 + threadIdx.x;   // 16384
        int k = idx >> 7, c = idx & 127;
        WT[c * DD + k] = f2b(W[idx]);
    } else {
        int base = ((bid - 192) * 256 + threadIdx.x) * 4;
        if (base + 3 < E) {
            int4 d4 = *(const int4*)(dst + base);
            atomicAdd(&cnt[d4.x], 1);
            atomicAdd(&cnt[d4.y], 1);
            atomicAdd(&cnt[d4.z], 1);
            atomicAdd(&cnt[d4.w], 1);
        } else {
            for (int e = base; e < E; ++e) atomicAdd(&cnt[dst[e]], 1);
        }
    }
}

// ---------------- hierarchical scan ----------------
__global__ __launch_bounds__(256) void k_scan1(const int* __restrict__ cnt, int* __restrict__ part, int N) {
    __shared__ int lds[256];
    int t = threadIdx.x;
    int i = blockIdx.x * 256 + t;
    lds[t] = (i < N) ? cnt[i] : 0;
    __syncthreads();
#pragma unroll
    for (int off = 128; off > 0; off >>= 1) {
        if (t < off) lds[t] += lds[t + off];
        __syncthreads();
    }
    if (t == 0) part[blockIdx.x] = lds[0];
}

__global__ __launch_bounds__(1024) void k_scan2(int* __restrict__ part, int* __restrict__ rowptr,
                                                int nblk, int N) {
    __shared__ int lds[1024];
    int t = threadIdx.x;
    int v = (t < nblk) ? part[t] : 0;
    lds[t] = v;
    __syncthreads();
    for (int off = 1; off < 1024; off <<= 1) {
        int u = (t >= off) ? lds[t - off] : 0;
        __syncthreads();
        lds[t] += u;
        __syncthreads();
    }
    if (t < nblk) part[t] = lds[t] - v;
    if (t == 1023) rowptr[N] = lds[1023];
}

// scan3 + dinv fused
__global__ __launch_bounds__(256) void k_scan3(const int* __restrict__ cnt, const int* __restrict__ part,
                                               int* __restrict__ rowptr, float* __restrict__ dinv, int N) {
    __shared__ int lds[256];
    int t = threadIdx.x;
    int i = blockIdx.x * 256 + t;
    int v = (i < N) ? cnt[i] : 0;
    lds[t] = v;
    __syncthreads();
    for (int off = 1; off < 256; off <<= 1) {
        int u = (t >= off) ? lds[t - off] : 0;
        __syncthreads();
        lds[t] += u;
        __syncthreads();
    }
    if (i < N) {
        rowptr[i] = part[blockIdx.x] + lds[t] - v;
        dinv[i] = rsqrtf((float)v + 1.0f);
    }
}

// ---------------- fill adjacency (single pass, src-only 4B payload) ----------------
__global__ __launch_bounds__(256) void k_fill(const int* __restrict__ src, const int* __restrict__ dst,
                                              const int* __restrict__ rowptr, int* __restrict__ cursor,
                                              int* __restrict__ adjS, int E) {
    int base = (blockIdx.x * 256 + threadIdx.x) * 4;
    if (base + 3 < E) {
        int4 s4 = *(const int4*)(src + base);
        int4 d4 = *(const int4*)(dst + base);
        int p0 = atomicAdd(&cursor[d4.x], 1);
        int p1 = atomicAdd(&cursor[d4.y], 1);
        int p2 = atomicAdd(&cursor[d4.z], 1);
        int p3 = atomicAdd(&cursor[d4.w], 1);
        adjS[rowptr[d4.x] + p0] = s4.x;
        adjS[rowptr[d4.y] + p1] = s4.y;
        adjS[rowptr[d4.z] + p2] = s4.z;
        adjS[rowptr[d4.w] + p3] = s4.w;
    } else {
        for (int e = base; e < E; ++e) {
            int s = src[e], d = dst[e];
            int pos = atomicAdd(&cursor[d], 1);
            adjS[rowptr[d] + pos] = s;
        }
    }
}

// ---------------- MFMA GEMM: HS_bf16[N,128] = dinv[r] * (X[N,128] @ W), 128-row tile ----------------
template <int IN_BF16>
__global__ __launch_bounds__(256) void k_gemm_mfma(const void* __restrict__ Xv,
                                                   const unsigned short* __restrict__ WT,
                                                   const float* __restrict__ dinv,
                                                   unsigned short* __restrict__ H, int N) {
    __shared__ __align__(16) unsigned short sB[DD * DD];    // 32 KB swizzled
    __shared__ __align__(16) unsigned short sA[DD * DD];    // 32 KB swizzled
    int tid = threadIdx.x;
    long row0 = (long)blockIdx.x * 128;

#pragma unroll
    for (int i = 0; i < 8; ++i) {
        int q = tid + 256 * i;
        int c = q >> 4, j = q & 15;
        short8 v = *(const short8*)(WT + q * 8);
        int byte = c * 256 + ((j * 16) ^ ((c & 7) << 4));
        *(short8*)((char*)sB + byte) = v;
    }
#pragma unroll
    for (int i = 0; i < 8; ++i) {
        int q = tid + 256 * i;
        int r = q >> 4, j = q & 15;
        short8 v;
        if (IN_BF16) {
#pragma unroll
            for (int z = 0; z < 8; ++z) v[z] = 0;
            if (row0 + r < N) v = *(const short8*)((const unsigned short*)Xv + (row0 + r) * DD + j * 8);
        } else {
            float4 a0 = make_float4(0.f, 0.f, 0.f, 0.f), a1 = a0;
            if (row0 + r < N) {
                const float4* p = (const float4*)((const float*)Xv + (row0 + r) * DD + j * 8);
                a0 = p[0];
                a1 = p[1];
            }
            v[0] = (short)f2b(a0.x); v[1] = (short)f2b(a0.y);
            v[2] = (short)f2b(a0.z); v[3] = (short)f2b(a0.w);
            v[4] = (short)f2b(a1.x); v[5] = (short)f2b(a1.y);
            v[6] = (short)f2b(a1.z); v[7] = (short)f2b(a1.w);
        }
        int byte = r * 256 + ((j * 16) ^ ((r & 7) << 4));
        *(short8*)((char*)sA + byte) = v;
    }
    __syncthreads();

    int w = tid >> 6, l = tid & 63;
    int lr = l & 15, kg = l >> 4;
    int ar0 = w * 32 + lr, ar1 = w * 32 + 16 + lr;
    f32x4 acc0[8] = {}, acc1[8] = {};

#pragma unroll
    for (int step = 0; step < 4; ++step) {
        int koff = step * 64 + kg * 16;
        short8 a0 = *(const short8*)((const char*)sA + ar0 * 256 + (koff ^ ((ar0 & 7) << 4)));
        short8 a1 = *(const short8*)((const char*)sA + ar1 * 256 + (koff ^ ((ar1 & 7) << 4)));
#pragma unroll
        for (int ct = 0; ct < 8; ++ct) {
            int c = ct * 16 + lr;
            short8 bf = *(const short8*)((const char*)sB + c * 256 + (koff ^ ((c & 7) << 4)));
            acc0[ct] = __builtin_amdgcn_mfma_f32_16x16x32_bf16(a0, bf, acc0[ct], 0, 0, 0);
            acc1[ct] = __builtin_amdgcn_mfma_f32_16x16x32_bf16(a1, bf, acc1[ct], 0, 0, 0);
        }
    }

    // dinv prescale: HS[r] = dinv[r] * h[r]
    float dv0[4], dv1[4];
#pragma unroll
    for (int reg = 0; reg < 4; ++reg) {
        long r = row0 + w * 32 + kg * 4 + reg;
        dv0[reg] = (r < N) ? dinv[r] : 0.f;
        dv1[reg] = (r + 16 < N) ? dinv[r + 16] : 0.f;
    }
#pragma unroll
    for (int ct = 0; ct < 8; ++ct) {
#pragma unroll
        for (int reg = 0; reg < 4; ++reg) {
            long r = row0 + w * 32 + kg * 4 + reg;
            if (r < N) H[r * DD + ct * 16 + lr] = f2b(dv0[reg] * acc0[ct][reg]);
            long r2 = r + 16;
            if (r2 < N) H[r2 * DD + ct * 16 + lr] = f2b(dv1[reg] * acc1[ct][reg]);
        }
    }
}

// ------- fused: aggregate (hs bf16) -> LN -> residual -> SiLU -> x_out bf16 -------
// Gather uses 32-lane x 8B row layout: each wave-load fetches TWO edges' rows
// (lanes 0-31 = even edge, 32-63 = odd edge) -> 2x memory-level parallelism per
// instruction vs the 64-lane x 4B layout (round 10/12 showed agg is MLP-limited).
template <int IN_BF16>
__global__ __launch_bounds__(256) void k_agg(const unsigned short* __restrict__ h, const void* __restrict__ xin,
                                             const int* __restrict__ rowptr, const int* __restrict__ adjS,
                                             const float* __restrict__ dinv, const float* __restrict__ b,
                                             const float* __restrict__ g, const float* __restrict__ be,
                                             unsigned int* __restrict__ xout, int N) {
    int row = blockIdx.x * 4 + (threadIdx.x >> 6);
    if (row >= N) return;
    int lane = threadIdx.x & 63;
    int half = lane >> 5, sl = lane & 31;
    const unsigned int* hu = (const unsigned int*)h;     // 64 x 4B per row
    const uint2* hu2 = (const uint2*)h;                  // 32 x 8B per row

    float dv = dinv[row];
    unsigned int us = hu[(size_t)row * 64 + lane];
    float selfx = b2f((unsigned short)(us & 0xFFFF));
    float selfy = b2f((unsigned short)(us >> 16));

    // neighbor sum in 32-lane layout: lane holds features sl*4..sl*4+3, edges of parity `half`
    float acc4[4] = {0.f, 0.f, 0.f, 0.f};

    int beg = rowptr[row], end = rowptr[row + 1];
    for (int j0 = beg; j0 < end; j0 += 64) {
        int myj = j0 + lane;
        int a = (myj < end) ? adjS[myj] : 0;
        int cnt = min(64, end - j0);
        int cntR = (cnt + 31) & ~31;
        for (int k0 = 0; k0 < cntR; k0 += 32) {
            uint2 un[16];
#pragma unroll
            for (int u = 0; u < 16; ++u) {
                int e = k0 + (u << 1) + half;
                int s = __shfl(a, e, 64);
                un[u] = hu2[(size_t)s * 32 + sl];
            }
#pragma unroll
            for (int u = 0; u < 16; ++u) {
                int e = k0 + (u << 1) + half;
                float m = (e < cnt) ? 1.0f : 0.0f;
                acc4[0] = fmaf(m, b2f((unsigned short)(un[u].x & 0xFFFF)), acc4[0]);
                acc4[1] = fmaf(m, b2f((unsigned short)(un[u].x >> 16)), acc4[1]);
                acc4[2] = fmaf(m, b2f((unsigned short)(un[u].y & 0xFFFF)), acc4[2]);
                acc4[3] = fmaf(m, b2f((unsigned short)(un[u].y >> 16)), acc4[3]);
            }
        }
    }
    // combine even/odd edge partial sums across the half-wave split
#pragma unroll
    for (int j = 0; j < 4; ++j) acc4[j] += __shfl_xor(acc4[j], 32, 64);

    // reshape 32-lane x 4 features -> 64-lane x 2 features:
    // lane M needs features (2M, 2M+1) = source lane (M>>1)&31, float pair (M&1)
    float v0 = __shfl(acc4[0], lane >> 1, 64);
    float v1 = __shfl(acc4[1], lane >> 1, 64);
    float v2 = __shfl(acc4[2], lane >> 1, 64);
    float v3 = __shfl(acc4[3], lane >> 1, 64);
    float nbrx = (lane & 1) ? v2 : v0;
    float nbry = (lane & 1) ? v3 : v1;

    float2 bv = ((const float2*)b)[lane];
    float ox = fmaf(dv, selfx + nbrx, bv.x);
    float oy = fmaf(dv, selfy + nbry, bv.y);

    // LayerNorm over 128
    float ssum = ox + oy;
#pragma unroll
    for (int o = 32; o > 0; o >>= 1) ssum += __shfl_xor(ssum, o, 64);
    float mu = ssum * (1.0f / 128.0f);
    float dx0 = ox - mu, dx1 = oy - mu;
    float vs = dx0 * dx0 + dx1 * dx1;
#pragma unroll
    for (int o = 32; o > 0; o >>= 1) vs += __shfl_xor(vs, o, 64);
    float rstd = rsqrtf(vs * (1.0f / 128.0f) + 1e-5f);

    float2 gv = ((const float2*)g)[lane];
    float2 bev = ((const float2*)be)[lane];
    float2 xv;
    if (IN_BF16) {
        unsigned int xu = ((const unsigned int*)xin)[(size_t)row * 64 + lane];
        xv = make_float2(b2f((unsigned short)(xu & 0xFFFF)), b2f((unsigned short)(xu >> 16)));
    } else {
        xv = ((const float2*)xin)[(size_t)row * 64 + lane];
    }
    float a0 = fmaf(dx0 * rstd, gv.x, bev.x) + xv.x;
    float a1 = fmaf(dx1 * rstd, gv.y, bev.y) + xv.y;
    a0 = a0 / (1.0f + expf(-a0));
    a1 = a1 / (1.0f + expf(-a1));
    xout[(size_t)row * 64 + lane] = ((unsigned int)f2b(a1) << 16) | (unsigned int)f2b(a0);
}

// ------- pool: one block per graph (batch sorted -> contiguous ranges), x bf16 -------
__global__ __launch_bounds__(256) void k_pool2(const unsigned int* __restrict__ x, const int* __restrict__ batch,
                                               float* __restrict__ out, int N) {
    int gi = blockIdx.x;
    int lo = 0, hi = N;
    while (lo < hi) { int m = (lo + hi) >> 1; if (batch[m] < gi) lo = m + 1; else hi = m; }
    int beg = lo;
    lo = beg; hi = N;
    while (lo < hi) { int m = (lo + hi) >> 1; if (batch[m] < gi + 1) lo = m + 1; else hi = m; }
    int end = lo;

    int tid = threadIdx.x;
    int wave = tid >> 6, lane = tid & 63;
    float2 acc = make_float2(0.f, 0.f);
    for (int r = beg + wave; r < end; r += 4) {
        unsigned int u = x[(size_t)r * 64 + lane];
        acc.x += b2f((unsigned short)(u & 0xFFFF));
        acc.y += b2f((unsigned short)(u >> 16));
    }
    __shared__ float part[4][DD];
    ((float2*)part[wave])[lane] = acc;
    __syncthreads();
    if (wave == 0) {
        float sx = 0.f, sy = 0.f;
#pragma unroll
        for (int w = 0; w < 4; ++w) {
            float2 v = ((const float2*)part[w])[lane];
            sx += v.x;
            sy += v.y;
        }
        float inv = 1.0f / fmaxf((float)(end - beg), 1.0f);
        ((float2*)(out + (size_t)gi * DD))[lane] = make_float2(sx * inv, sy * inv);
    }
}

extern "C" void kernel_launch(void* const* d_in, const int* in_sizes, int n_in,
                              void* d_out, int out_size, void* d_ws, size_t ws_size,
                              hipStream_t stream) {
    const float* x = (const float*)d_in[0];
    const int* edge = (const int*)d_in[1];
    const int* batch = (const int*)d_in[2];
    const float* W[3] = {(const float*)d_in[3], (const float*)d_in[7], (const float*)d_in[11]};
    const float* b[3] = {(const float*)d_in[4], (const float*)d_in[8], (const float*)d_in[12]};
    const float* g[3] = {(const float*)d_in[5], (const float*)d_in[9], (const float*)d_in[13]};
    const float* be[3] = {(const float*)d_in[6], (const float*)d_in[10], (const float*)d_in[14]};

    int N = in_sizes[0] / DD;
    int E = in_sizes[1] / 2;
    int G = out_size / DD;
    const int* srcI = edge;
    const int* dstI = edge + E;

    int nblk = (N + 255) / 256;

    char* ws = (char*)d_ws;
    size_t ND = (size_t)N * DD;
    unsigned int* bufX = (unsigned int*)ws;           ws += ND * 2;   // x state, bf16
    unsigned short* bufH = (unsigned short*)ws;       ws += ND * 2;   // hs = dinv*h, bf16
    unsigned short* wt[3];
    for (int l = 0; l < 3; ++l) { wt[l] = (unsigned short*)ws; ws += (size_t)DD * DD * 2; }
    float* dinv = (float*)ws;                         ws += (size_t)N * 4;
    int* cnt = (int*)ws;                              ws += (size_t)N * 4;
    int* cursor = (int*)ws;                           ws += (size_t)N * 4;
    int* rowptr = (int*)ws;                           ws += (size_t)(N + 1) * 4;
    int* part = (int*)ws;                             ws += (size_t)nblk * 4;
    int* adjS = (int*)ws;

    hipMemsetAsync(cnt, 0, (size_t)N * 2 * 4, stream);   // cnt + cursor adjacent

    int histblk = (E + 1023) / 1024;
    k_setup<<<192 + histblk, 256, 0, stream>>>(dstI, cnt, E, W[0], W[1], W[2], wt[0], wt[1], wt[2]);
    k_scan1<<<nblk, 256, 0, stream>>>(cnt, part, N);
    k_scan2<<<1, 1024, 0, stream>>>(part, rowptr, nblk, N);
    k_scan3<<<nblk, 256, 0, stream>>>(cnt, part, rowptr, dinv, N);
    k_fill<<<(E / 4 + 255) / 256 + 1, 256, 0, stream>>>(srcI, dstI, rowptr, cursor, adjS, E);

    int gblk = (N + 127) / 128, ablk = (N + 3) / 4;
    // layer 0: fp32 input
    k_gemm_mfma<0><<<gblk, 256, 0, stream>>>(x, wt[0], dinv, bufH, N);
    k_agg<0><<<ablk, 256, 0, stream>>>(bufH, x, rowptr, adjS, dinv, b[0], g[0], be[0], bufX, N);
    // layers 1,2: bf16 state (in-place safe: each thread reads own row before writing)
    for (int l = 1; l < 3; ++l) {
        k_gemm_mfma<1><<<gblk, 256, 0, stream>>>(bufX, wt[l], dinv, bufH, N);
        k_agg<1><<<ablk, 256, 0, stream>>>(bufH, bufX, rowptr, adjS, dinv, b[l], g[l], be[l], bufX, N);
    }

    k_pool2<<<G, 256, 0, stream>>>(bufX, batch, (float*)d_out, N);
}

// Round 17
// 248.983 us; speedup vs baseline: 1.1281x; 1.1281x over previous
//
#include <hip/hip_runtime.h>
#include <math.h>

#define DD 128

typedef __attribute__((ext_vector_type(8))) short short8;
typedef __attribute__((ext_vector_type(4))) float f32x4;

__device__ __forceinline__ unsigned short f2b(float f) {
    unsigned int x = __float_as_uint(f);
    return (unsigned short)((x + 0x7FFFu + ((x >> 16) & 1u)) >> 16);   // RNE bf16
}
__device__ __forceinline__ float b2f(unsigned short u) {
    return __uint_as_float(((unsigned int)u) << 16);
}

// ---------------- fused setup: blocks [0,192) transpose W->bf16, rest histogram dst ----------------
__global__ __launch_bounds__(256) void k_setup(const int* __restrict__ dst, int* __restrict__ cnt, int E,
                                               const float* __restrict__ W0, const float* __restrict__ W1,
                                               const float* __restrict__ W2, unsigned short* __restrict__ T0,
                                               unsigned short* __restrict__ T1, unsigned short* __restrict__ T2) {
    int bid = blockIdx.x;
    if (bid < 192) {
        int l = bid >> 6;
        const float* W = (l == 0) ? W0 : (l == 1) ? W1 : W2;
        unsigned short* WT = (l == 0) ? T0 : (l == 1) ? T1 : T2;
        int idx = (bid & 63) * 256 + threadIdx.x;   // 16384
        int k = idx >> 7, c = idx & 127;
        WT[c * DD + k] = f2b(W[idx]);
    } else {
        int base = ((bid - 192) * 256 + threadIdx.x) * 4;
        if (base + 3 < E) {
            int4 d4 = *(const int4*)(dst + base);
            atomicAdd(&cnt[d4.x], 1);
            atomicAdd(&cnt[d4.y], 1);
            atomicAdd(&cnt[d4.z], 1);
            atomicAdd(&cnt[d4.w], 1);
        } else {
            for (int e = base; e < E; ++e) atomicAdd(&cnt[dst[e]], 1);
        }
    }
}

// ---------------- hierarchical scan ----------------
__global__ __launch_bounds__(256) void k_scan1(const int* __restrict__ cnt, int* __restrict__ part, int N) {
    __shared__ int lds[256];
    int t = threadIdx.x;
    int i = blockIdx.x * 256 + t;
    lds[t] = (i < N) ? cnt[i] : 0;
    __syncthreads();
#pragma unroll
    for (int off = 128; off > 0; off >>= 1) {
        if (t < off) lds[t] += lds[t + off];
        __syncthreads();
    }
    if (t == 0) part[blockIdx.x] = lds[0];
}

__global__ __launch_bounds__(1024) void k_scan2(int* __restrict__ part, int* __restrict__ rowptr,
                                                int nblk, int N) {
    __shared__ int lds[1024];
    int t = threadIdx.x;
    int v = (t < nblk) ? part[t] : 0;
    lds[t] = v;
    __syncthreads();
    for (int off = 1; off < 1024; off <<= 1) {
        int u = (t >= off) ? lds[t - off] : 0;
        __syncthreads();
        lds[t] += u;
        __syncthreads();
    }
    if (t < nblk) part[t] = lds[t] - v;
    if (t == 1023) rowptr[N] = lds[1023];
}

// scan3 + dinv fused
__global__ __launch_bounds__(256) void k_scan3(const int* __restrict__ cnt, const int* __restrict__ part,
                                               int* __restrict__ rowptr, float* __restrict__ dinv, int N) {
    __shared__ int lds[256];
    int t = threadIdx.x;
    int i = blockIdx.x * 256 + t;
    int v = (i < N) ? cnt[i] : 0;
    lds[t] = v;
    __syncthreads();
    for (int off = 1; off < 256; off <<= 1) {
        int u = (t >= off) ? lds[t - off] : 0;
        __syncthreads();
        lds[t] += u;
        __syncthreads();
    }
    if (i < N) {
        rowptr[i] = part[blockIdx.x] + lds[t] - v;
        dinv[i] = rsqrtf((float)v + 1.0f);
    }
}

// ---------------- fused: layer-0 GEMM (blocks < gblk) + adjacency fill (blocks >= gblk) ----------------
// The two are independent; fusing lets the scatter-bound fill (43us, VALU 0.5%) hide the
// compute-bound gemm0 (~13us) instead of running serially. Fill path: no LDS use, no syncthreads.
template <int IN_BF16>
__global__ __launch_bounds__(256) void k_gemm_mfma(const void* __restrict__ Xv,
                                                   const unsigned short* __restrict__ WT,
                                                   const float* __restrict__ dinv,
                                                   unsigned short* __restrict__ H, int N, int gblk,
                                                   const int* __restrict__ src, const int* __restrict__ dst,
                                                   const int* __restrict__ rowptr, int* __restrict__ cursor,
                                                   int* __restrict__ adjS, int E) {
    __shared__ __align__(16) unsigned short sB[DD * DD];    // 32 KB swizzled
    __shared__ __align__(16) unsigned short sA[DD * DD];    // 32 KB swizzled
    int tid = threadIdx.x;

    if ((int)blockIdx.x >= gblk) {   // ---- fill part (block-uniform branch, early return) ----
        int base = (((int)blockIdx.x - gblk) * 256 + tid) * 4;
        if (base + 3 < E) {
            int4 s4 = *(const int4*)(src + base);
            int4 d4 = *(const int4*)(dst + base);
            int p0 = atomicAdd(&cursor[d4.x], 1);
            int p1 = atomicAdd(&cursor[d4.y], 1);
            int p2 = atomicAdd(&cursor[d4.z], 1);
            int p3 = atomicAdd(&cursor[d4.w], 1);
            adjS[rowptr[d4.x] + p0] = s4.x;
            adjS[rowptr[d4.y] + p1] = s4.y;
            adjS[rowptr[d4.z] + p2] = s4.z;
            adjS[rowptr[d4.w] + p3] = s4.w;
        } else {
            for (int e = base; e < E && e >= 0; ++e) {
                int s = src[e], d = dst[e];
                int pos = atomicAdd(&cursor[d], 1);
                adjS[rowptr[d] + pos] = s;
            }
        }
        return;
    }

    long row0 = (long)blockIdx.x * 128;

#pragma unroll
    for (int i = 0; i < 8; ++i) {
        int q = tid + 256 * i;
        int c = q >> 4, j = q & 15;
        short8 v = *(const short8*)(WT + q * 8);
        int byte = c * 256 + ((j * 16) ^ ((c & 7) << 4));
        *(short8*)((char*)sB + byte) = v;
    }
#pragma unroll
    for (int i = 0; i < 8; ++i) {
        int q = tid + 256 * i;
        int r = q >> 4, j = q & 15;
        short8 v;
        if (IN_BF16) {
#pragma unroll
            for (int z = 0; z < 8; ++z) v[z] = 0;
            if (row0 + r < N) v = *(const short8*)((const unsigned short*)Xv + (row0 + r) * DD + j * 8);
        } else {
            float4 a0 = make_float4(0.f, 0.f, 0.f, 0.f), a1 = a0;
            if (row0 + r < N) {
                const float4* p = (const float4*)((const float*)Xv + (row0 + r) * DD + j * 8);
                a0 = p[0];
                a1 = p[1];
            }
            v[0] = (short)f2b(a0.x); v[1] = (short)f2b(a0.y);
            v[2] = (short)f2b(a0.z); v[3] = (short)f2b(a0.w);
            v[4] = (short)f2b(a1.x); v[5] = (short)f2b(a1.y);
            v[6] = (short)f2b(a1.z); v[7] = (short)f2b(a1.w);
        }
        int byte = r * 256 + ((j * 16) ^ ((r & 7) << 4));
        *(short8*)((char*)sA + byte) = v;
    }
    __syncthreads();

    int w = tid >> 6, l = tid & 63;
    int lr = l & 15, kg = l >> 4;
    int ar0 = w * 32 + lr, ar1 = w * 32 + 16 + lr;
    f32x4 acc0[8] = {}, acc1[8] = {};

#pragma unroll
    for (int step = 0; step < 4; ++step) {
        int koff = step * 64 + kg * 16;
        short8 a0 = *(const short8*)((const char*)sA + ar0 * 256 + (koff ^ ((ar0 & 7) << 4)));
        short8 a1 = *(const short8*)((const char*)sA + ar1 * 256 + (koff ^ ((ar1 & 7) << 4)));
#pragma unroll
        for (int ct = 0; ct < 8; ++ct) {
            int c = ct * 16 + lr;
            short8 bf = *(const short8*)((const char*)sB + c * 256 + (koff ^ ((c & 7) << 4)));
            acc0[ct] = __builtin_amdgcn_mfma_f32_16x16x32_bf16(a0, bf, acc0[ct], 0, 0, 0);
            acc1[ct] = __builtin_amdgcn_mfma_f32_16x16x32_bf16(a1, bf, acc1[ct], 0, 0, 0);
        }
    }

    // dinv prescale: HS[r] = dinv[r] * h[r]
    float dv0[4], dv1[4];
#pragma unroll
    for (int reg = 0; reg < 4; ++reg) {
        long r = row0 + w * 32 + kg * 4 + reg;
        dv0[reg] = (r < N) ? dinv[r] : 0.f;
        dv1[reg] = (r + 16 < N) ? dinv[r + 16] : 0.f;
    }
#pragma unroll
    for (int ct = 0; ct < 8; ++ct) {
#pragma unroll
        for (int reg = 0; reg < 4; ++reg) {
            long r = row0 + w * 32 + kg * 4 + reg;
            if (r < N) H[r * DD + ct * 16 + lr] = f2b(dv0[reg] * acc0[ct][reg]);
            long r2 = r + 16;
            if (r2 < N) H[r2 * DD + ct * 16 + lr] = f2b(dv1[reg] * acc1[ct][reg]);
        }
    }
}

// ------- fused: aggregate (hs bf16, 64-lane x 4B gather, uniform-index shfl) -> LN -> SiLU -------
// Round-16 lesson: lane-dependent shfl index -> ds_bpermute, VALU-bound (62%), slower.
// Uniform index -> v_readlane broadcast; 16 independent gathers in flight (round-10 win).
template <int IN_BF16>
__global__ __launch_bounds__(256) void k_agg(const unsigned short* __restrict__ h, const void* __restrict__ xin,
                                             const int* __restrict__ rowptr, const int* __restrict__ adjS,
                                             const float* __restrict__ dinv, const float* __restrict__ b,
                                             const float* __restrict__ g, const float* __restrict__ be,
                                             unsigned int* __restrict__ xout, int N) {
    int row = blockIdx.x * 4 + (threadIdx.x >> 6);
    if (row >= N) return;
    int lane = threadIdx.x & 63;
    const unsigned int* hu = (const unsigned int*)h;

    float dv = dinv[row];
    unsigned int us = hu[(size_t)row * 64 + lane];
    float selfx = b2f((unsigned short)(us & 0xFFFF));
    float selfy = b2f((unsigned short)(us >> 16));
    float2 acc = make_float2(0.f, 0.f);

    int beg = rowptr[row], end = rowptr[row + 1];
    for (int j0 = beg; j0 < end; j0 += 64) {
        int myj = j0 + lane;
        int a = (myj < end) ? adjS[myj] : 0;
        int cnt = min(64, end - j0);
        int cntR = (cnt + 15) & ~15;
        for (int k0 = 0; k0 < cntR; k0 += 16) {
            unsigned int un[16];
#pragma unroll
            for (int u = 0; u < 16; ++u) {
                int s = __shfl(a, k0 + u, 64);
                un[u] = hu[(size_t)s * 64 + lane];
            }
#pragma unroll
            for (int u = 0; u < 16; ++u) {
                float m = (k0 + u < cnt) ? 1.0f : 0.0f;   // wave-uniform mask
                acc.x = fmaf(m, b2f((unsigned short)(un[u] & 0xFFFF)), acc.x);
                acc.y = fmaf(m, b2f((unsigned short)(un[u] >> 16)), acc.y);
            }
        }
    }

    float2 bv = ((const float2*)b)[lane];
    float ox = fmaf(dv, selfx + acc.x, bv.x);
    float oy = fmaf(dv, selfy + acc.y, bv.y);

    // LayerNorm over 128
    float ssum = ox + oy;
#pragma unroll
    for (int o = 32; o > 0; o >>= 1) ssum += __shfl_xor(ssum, o, 64);
    float mu = ssum * (1.0f / 128.0f);
    float dx0 = ox - mu, dx1 = oy - mu;
    float vs = dx0 * dx0 + dx1 * dx1;
#pragma unroll
    for (int o = 32; o > 0; o >>= 1) vs += __shfl_xor(vs, o, 64);
    float rstd = rsqrtf(vs * (1.0f / 128.0f) + 1e-5f);

    float2 gv = ((const float2*)g)[lane];
    float2 bev = ((const float2*)be)[lane];
    float2 xv;
    if (IN_BF16) {
        unsigned int xu = ((const unsigned int*)xin)[(size_t)row * 64 + lane];
        xv = make_float2(b2f((unsigned short)(xu & 0xFFFF)), b2f((unsigned short)(xu >> 16)));
    } else {
        xv = ((const float2*)xin)[(size_t)row * 64 + lane];
    }
    float a0 = fmaf(dx0 * rstd, gv.x, bev.x) + xv.x;
    float a1 = fmaf(dx1 * rstd, gv.y, bev.y) + xv.y;
    a0 = a0 / (1.0f + expf(-a0));
    a1 = a1 / (1.0f + expf(-a1));
    xout[(size_t)row * 64 + lane] = ((unsigned int)f2b(a1) << 16) | (unsigned int)f2b(a0);
}

// ------- pool: one block per graph (batch sorted -> contiguous ranges), x bf16 -------
__global__ __launch_bounds__(256) void k_pool2(const unsigned int* __restrict__ x, const int* __restrict__ batch,
                                               float* __restrict__ out, int N) {
    int gi = blockIdx.x;
    int lo = 0, hi = N;
    while (lo < hi) { int m = (lo + hi) >> 1; if (batch[m] < gi) lo = m + 1; else hi = m; }
    int beg = lo;
    lo = beg; hi = N;
    while (lo < hi) { int m = (lo + hi) >> 1; if (batch[m] < gi + 1) lo = m + 1; else hi = m; }
    int end = lo;

    int tid = threadIdx.x;
    int wave = tid >> 6, lane = tid & 63;
    float2 acc = make_float2(0.f, 0.f);
    for (int r = beg + wave; r < end; r += 4) {
        unsigned int u = x[(size_t)r * 64 + lane];
        acc.x += b2f((unsigned short)(u & 0xFFFF));
        acc.y += b2f((unsigned short)(u >> 16));
    }
    __shared__ float part[4][DD];
    ((float2*)part[wave])[lane] = acc;
    __syncthreads();
    if (wave == 0) {
        float sx = 0.f, sy = 0.f;
#pragma unroll
        for (int w = 0; w < 4; ++w) {
            float2 v = ((const float2*)part[w])[lane];
            sx += v.x;
            sy += v.y;
        }
        float inv = 1.0f / fmaxf((float)(end - beg), 1.0f);
        ((float2*)(out + (size_t)gi * DD))[lane] = make_float2(sx * inv, sy * inv);
    }
}

extern "C" void kernel_launch(void* const* d_in, const int* in_sizes, int n_in,
                              void* d_out, int out_size, void* d_ws, size_t ws_size,
                              hipStream_t stream) {
    const float* x = (const float*)d_in[0];
    const int* edge = (const int*)d_in[1];
    const int* batch = (const int*)d_in[2];
    const float* W[3] = {(const float*)d_in[3], (const float*)d_in[7], (const float*)d_in[11]};
    const float* b[3] = {(const float*)d_in[4], (const float*)d_in[8], (const float*)d_in[12]};
    const float* g[3] = {(const float*)d_in[5], (const float*)d_in[9], (const float*)d_in[13]};
    const float* be[3] = {(const float*)d_in[6], (const float*)d_in[10], (const float*)d_in[14]};

    int N = in_sizes[0] / DD;
    int E = in_sizes[1] / 2;
    int G = out_size / DD;
    const int* srcI = edge;
    const int* dstI = edge + E;

    int nblk = (N + 255) / 256;

    char* ws = (char*)d_ws;
    size_t ND = (size_t)N * DD;
    unsigned int* bufX = (unsigned int*)ws;           ws += ND * 2;   // x state, bf16
    unsigned short* bufH = (unsigned short*)ws;       ws += ND * 2;   // hs = dinv*h, bf16
    unsigned short* wt[3];
    for (int l = 0; l < 3; ++l) { wt[l] = (unsigned short*)ws; ws += (size_t)DD * DD * 2; }
    float* dinv = (float*)ws;                         ws += (size_t)N * 4;
    int* cnt = (int*)ws;                              ws += (size_t)N * 4;
    int* cursor = (int*)ws;                           ws += (size_t)N * 4;
    int* rowptr = (int*)ws;                           ws += (size_t)(N + 1) * 4;
    int* part = (int*)ws;                             ws += (size_t)nblk * 4;
    int* adjS = (int*)ws;

    hipMemsetAsync(cnt, 0, (size_t)N * 2 * 4, stream);   // cnt + cursor adjacent

    int histblk = (E + 1023) / 1024;
    k_setup<<<192 + histblk, 256, 0, stream>>>(dstI, cnt, E, W[0], W[1], W[2], wt[0], wt[1], wt[2]);
    k_scan1<<<nblk, 256, 0, stream>>>(cnt, part, N);
    k_scan2<<<1, 1024, 0, stream>>>(part, rowptr, nblk, N);
    k_scan3<<<nblk, 256, 0, stream>>>(cnt, part, rowptr, dinv, N);

    int gblk = (N + 127) / 128, ablk = (N + 3) / 4;
    int fillblk = (E / 4 + 255) / 256 + 1;
    // layer 0: fp32 input; fill fused into the same launch (independent work, overlaps)
    k_gemm_mfma<0><<<gblk + fillblk, 256, 0, stream>>>(x, wt[0], dinv, bufH, N, gblk,
                                                       srcI, dstI, rowptr, cursor, adjS, E);
    k_agg<0><<<ablk, 256, 0, stream>>>(bufH, x, rowptr, adjS, dinv, b[0], g[0], be[0], bufX, N);
    // layers 1,2: bf16 state (in-place safe: each thread reads own row before writing)
    for (int l = 1; l < 3; ++l) {
        k_gemm_mfma<1><<<gblk, 256, 0, stream>>>(bufX, wt[l], dinv, bufH, N, gblk,
                                                 srcI, dstI, rowptr, cursor, adjS, E);
        k_agg<1><<<ablk, 256, 0, stream>>>(bufH, bufX, rowptr, adjS, dinv, b[l], g[l], be[l], bufX, N);
    }

    k_pool2<<<G, 256, 0, stream>>>(bufX, batch, (float*)d_out, N);
}

// Round 19
// 232.474 us; speedup vs baseline: 1.2082x; 1.0710x over previous
//
#include <hip/hip_runtime.h>
#include <math.h>

#define DD 128

typedef __attribute__((ext_vector_type(8))) short short8;
typedef __attribute__((ext_vector_type(4))) float f32x4;

__device__ __forceinline__ unsigned short f2b(float f) {
    unsigned int x = __float_as_uint(f);
    return (unsigned short)((x + 0x7FFFu + ((x >> 16) & 1u)) >> 16);   // RNE bf16
}
__device__ __forceinline__ float b2f(unsigned short u) {
    return __uint_as_float(((unsigned int)u) << 16);
}

// ---------------- fused setup: blocks [0,192) transpose W->bf16, rest histogram dst ----------------
// Histogram captures each edge's rank-within-dst from the atomic return value, so the
// later fill needs NO atomics (round-17 A/B: is fill atomic-serialized or store-bound?).
__global__ __launch_bounds__(256) void k_setup(const int* __restrict__ dst, int* __restrict__ cnt,
                                               int* __restrict__ rank, int E,
                                               const float* __restrict__ W0, const float* __restrict__ W1,
                                               const float* __restrict__ W2, unsigned short* __restrict__ T0,
                                               unsigned short* __restrict__ T1, unsigned short* __restrict__ T2) {
    int bid = blockIdx.x;
    if (bid < 192) {
        int l = bid >> 6;
        const float* W = (l == 0) ? W0 : (l == 1) ? W1 : W2;
        unsigned short* WT = (l == 0) ? T0 : (l == 1) ? T1 : T2;
        int idx = (bid & 63) * 256 + threadIdx.x;   // 16384
        int k = idx >> 7, c = idx & 127;
        WT[c * DD + k] = f2b(W[idx]);
    } else {
        int base = ((bid - 192) * 256 + threadIdx.x) * 4;
        if (base + 3 < E) {
            int4 d4 = *(const int4*)(dst + base);
            int r0 = atomicAdd(&cnt[d4.x], 1);
            int r1 = atomicAdd(&cnt[d4.y], 1);
            int r2 = atomicAdd(&cnt[d4.z], 1);
            int r3 = atomicAdd(&cnt[d4.w], 1);
            *(int4*)(rank + base) = make_int4(r0, r1, r2, r3);
        } else {
            for (int e = base; e < E; ++e) rank[e] = atomicAdd(&cnt[dst[e]], 1);
        }
    }
}

// ---------------- scan phase 1: per-block sums ----------------
__global__ __launch_bounds__(256) void k_scan1(const int* __restrict__ cnt, int* __restrict__ part, int N) {
    __shared__ int lds[256];
    int t = threadIdx.x;
    int i = blockIdx.x * 256 + t;
    lds[t] = (i < N) ? cnt[i] : 0;
    __syncthreads();
#pragma unroll
    for (int off = 128; off > 0; off >>= 1) {
        if (t < off) lds[t] += lds[t + off];
        __syncthreads();
    }
    if (t == 0) part[blockIdx.x] = lds[0];
}

// ---------------- scan phase 2 (merged): every block scans the partials in LDS, then local scan ----------------
__global__ __launch_bounds__(256) void k_scan3(const int* __restrict__ cnt, const int* __restrict__ part,
                                               int* __restrict__ rowptr, float* __restrict__ dinv,
                                               int N, int nblk) {
    __shared__ int sp[256];
    __shared__ int lds[256];
    int t = threadIdx.x;
    sp[t] = (t < nblk) ? part[t] : 0;
    __syncthreads();
    for (int off = 1; off < 256; off <<= 1) {
        int u = (t >= off) ? sp[t - off] : 0;
        __syncthreads();
        sp[t] += u;
        __syncthreads();
    }
    int blockOff = (blockIdx.x > 0) ? sp[blockIdx.x - 1] : 0;

    int i = blockIdx.x * 256 + t;
    int v = (i < N) ? cnt[i] : 0;
    lds[t] = v;
    __syncthreads();
    for (int off = 1; off < 256; off <<= 1) {
        int u = (t >= off) ? lds[t - off] : 0;
        __syncthreads();
        lds[t] += u;
        __syncthreads();
    }
    if (i < N) {
        rowptr[i] = blockOff + lds[t] - v;
        dinv[i] = rsqrtf((float)v + 1.0f);
    }
    if (blockIdx.x == 0 && t == 0) rowptr[N] = sp[nblk - 1];   // = E
}

// ---------------- fused: layer-0 GEMM (blocks < gblk) + atomic-free adjacency scatter ----------------
template <int IN_BF16>
__global__ __launch_bounds__(256) void k_gemm_mfma(const void* __restrict__ Xv,
                                                   const unsigned short* __restrict__ WT,
                                                   const float* __restrict__ dinv,
                                                   unsigned short* __restrict__ H, int N, int gblk,
                                                   const int* __restrict__ src, const int* __restrict__ dst,
                                                   const int* __restrict__ rank,
                                                   const int* __restrict__ rowptr,
                                                   int* __restrict__ adjS, int E) {
    __shared__ __align__(16) unsigned short sB[DD * DD];    // 32 KB swizzled
    __shared__ __align__(16) unsigned short sA[DD * DD];    // 32 KB swizzled
    int tid = threadIdx.x;

    if ((int)blockIdx.x >= gblk) {   // ---- scatter part (block-uniform branch, no LDS, no sync) ----
        int base = (((int)blockIdx.x - gblk) * 256 + tid) * 4;
        if (base + 3 < E) {
            int4 s4 = *(const int4*)(src + base);
            int4 d4 = *(const int4*)(dst + base);
            int4 r4 = *(const int4*)(rank + base);
            adjS[rowptr[d4.x] + r4.x] = s4.x;
            adjS[rowptr[d4.y] + r4.y] = s4.y;
            adjS[rowptr[d4.z] + r4.z] = s4.z;
            adjS[rowptr[d4.w] + r4.w] = s4.w;
        } else {
            for (int e = base; e < E && e >= 0; ++e)
                adjS[rowptr[dst[e]] + rank[e]] = src[e];
        }
        return;
    }

    long row0 = (long)blockIdx.x * 128;

#pragma unroll
    for (int i = 0; i < 8; ++i) {
        int q = tid + 256 * i;
        int c = q >> 4, j = q & 15;
        short8 v = *(const short8*)(WT + q * 8);
        int byte = c * 256 + ((j * 16) ^ ((c & 7) << 4));
        *(short8*)((char*)sB + byte) = v;
    }
#pragma unroll
    for (int i = 0; i < 8; ++i) {
        int q = tid + 256 * i;
        int r = q >> 4, j = q & 15;
        short8 v;
        if (IN_BF16) {
#pragma unroll
            for (int z = 0; z < 8; ++z) v[z] = 0;
            if (row0 + r < N) v = *(const short8*)((const unsigned short*)Xv + (row0 + r) * DD + j * 8);
        } else {
            float4 a0 = make_float4(0.f, 0.f, 0.f, 0.f), a1 = a0;
            if (row0 + r < N) {
                const float4* p = (const float4*)((const float*)Xv + (row0 + r) * DD + j * 8);
                a0 = p[0];
                a1 = p[1];
            }
            v[0] = (short)f2b(a0.x); v[1] = (short)f2b(a0.y);
            v[2] = (short)f2b(a0.z); v[3] = (short)f2b(a0.w);
            v[4] = (short)f2b(a1.x); v[5] = (short)f2b(a1.y);
            v[6] = (short)f2b(a1.z); v[7] = (short)f2b(a1.w);
        }
        int byte = r * 256 + ((j * 16) ^ ((r & 7) << 4));
        *(short8*)((char*)sA + byte) = v;
    }
    __syncthreads();

    int w = tid >> 6, l = tid & 63;
    int lr = l & 15, kg = l >> 4;
    int ar0 = w * 32 + lr, ar1 = w * 32 + 16 + lr;
    f32x4 acc0[8] = {}, acc1[8] = {};

#pragma unroll
    for (int step = 0; step < 4; ++step) {
        int koff = step * 64 + kg * 16;
        short8 a0 = *(const short8*)((const char*)sA + ar0 * 256 + (koff ^ ((ar0 & 7) << 4)));
        short8 a1 = *(const short8*)((const char*)sA + ar1 * 256 + (koff ^ ((ar1 & 7) << 4)));
#pragma unroll
        for (int ct = 0; ct < 8; ++ct) {
            int c = ct * 16 + lr;
            short8 bf = *(const short8*)((const char*)sB + c * 256 + (koff ^ ((c & 7) << 4)));
            acc0[ct] = __builtin_amdgcn_mfma_f32_16x16x32_bf16(a0, bf, acc0[ct], 0, 0, 0);
            acc1[ct] = __builtin_amdgcn_mfma_f32_16x16x32_bf16(a1, bf, acc1[ct], 0, 0, 0);
        }
    }

    // dinv prescale: HS[r] = dinv[r] * h[r]
    float dv0[4], dv1[4];
#pragma unroll
    for (int reg = 0; reg < 4; ++reg) {
        long r = row0 + w * 32 + kg * 4 + reg;
        dv0[reg] = (r < N) ? dinv[r] : 0.f;
        dv1[reg] = (r + 16 < N) ? dinv[r + 16] : 0.f;
    }
#pragma unroll
    for (int ct = 0; ct < 8; ++ct) {
#pragma unroll
        for (int reg = 0; reg < 4; ++reg) {
            long r = row0 + w * 32 + kg * 4 + reg;
            if (r < N) H[r * DD + ct * 16 + lr] = f2b(dv0[reg] * acc0[ct][reg]);
            long r2 = r + 16;
            if (r2 < N) H[r2 * DD + ct * 16 + lr] = f2b(dv1[reg] * acc1[ct][reg]);
        }
    }
}

// ------- fused: aggregate (hs bf16, 64-lane x 4B gather, uniform-index shfl) -> LN -> SiLU -------
template <int IN_BF16>
__global__ __launch_bounds__(256) void k_agg(const unsigned short* __restrict__ h, const void* __restrict__ xin,
                                             const int* __restrict__ rowptr, const int* __restrict__ adjS,
                                             const float* __restrict__ dinv, const float* __restrict__ b,
                                             const float* __restrict__ g, const float* __restrict__ be,
                                             unsigned int* __restrict__ xout, int N) {
    int row = blockIdx.x * 4 + (threadIdx.x >> 6);
    if (row >= N) return;
    int lane = threadIdx.x & 63;
    const unsigned int* hu = (const unsigned int*)h;

    float dv = dinv[row];
    unsigned int us = hu[(size_t)row * 64 + lane];
    float selfx = b2f((unsigned short)(us & 0xFFFF));
    float selfy = b2f((unsigned short)(us >> 16));
    float2 acc = make_float2(0.f, 0.f);

    int beg = rowptr[row], end = rowptr[row + 1];
    for (int j0 = beg; j0 < end; j0 += 64) {
        int myj = j0 + lane;
        int a = (myj < end) ? adjS[myj] : 0;
        int cnt = min(64, end - j0);
        int cntR = (cnt + 15) & ~15;
        for (int k0 = 0; k0 < cntR; k0 += 16) {
            unsigned int un[16];
#pragma unroll
            for (int u = 0; u < 16; ++u) {
                int s = __shfl(a, k0 + u, 64);
                un[u] = hu[(size_t)s * 64 + lane];
            }
#pragma unroll
            for (int u = 0; u < 16; ++u) {
                float m = (k0 + u < cnt) ? 1.0f : 0.0f;   // wave-uniform mask
                acc.x = fmaf(m, b2f((unsigned short)(un[u] & 0xFFFF)), acc.x);
                acc.y = fmaf(m, b2f((unsigned short)(un[u] >> 16)), acc.y);
            }
        }
    }

    float2 bv = ((const float2*)b)[lane];
    float ox = fmaf(dv, selfx + acc.x, bv.x);
    float oy = fmaf(dv, selfy + acc.y, bv.y);

    // LayerNorm over 128
    float ssum = ox + oy;
#pragma unroll
    for (int o = 32; o > 0; o >>= 1) ssum += __shfl_xor(ssum, o, 64);
    float mu = ssum * (1.0f / 128.0f);
    float dx0 = ox - mu, dx1 = oy - mu;
    float vs = dx0 * dx0 + dx1 * dx1;
#pragma unroll
    for (int o = 32; o > 0; o >>= 1) vs += __shfl_xor(vs, o, 64);
    float rstd = rsqrtf(vs * (1.0f / 128.0f) + 1e-5f);

    float2 gv = ((const float2*)g)[lane];
    float2 bev = ((const float2*)be)[lane];
    float2 xv;
    if (IN_BF16) {
        unsigned int xu = ((const unsigned int*)xin)[(size_t)row * 64 + lane];
        xv = make_float2(b2f((unsigned short)(xu & 0xFFFF)), b2f((unsigned short)(xu >> 16)));
    } else {
        xv = ((const float2*)xin)[(size_t)row * 64 + lane];
    }
    float a0 = fmaf(dx0 * rstd, gv.x, bev.x) + xv.x;
    float a1 = fmaf(dx1 * rstd, gv.y, bev.y) + xv.y;
    a0 = a0 / (1.0f + expf(-a0));
    a1 = a1 / (1.0f + expf(-a1));
    xout[(size_t)row * 64 + lane] = ((unsigned int)f2b(a1) << 16) | (unsigned int)f2b(a0);
}

// ------- pool: one block per graph (batch sorted -> contiguous ranges), x bf16 -------
__global__ __launch_bounds__(256) void k_pool2(const unsigned int* __restrict__ x, const int* __restrict__ batch,
                                               float* __restrict__ out, int N) {
    int gi = blockIdx.x;
    int lo = 0, hi = N;
    while (lo < hi) { int m = (lo + hi) >> 1; if (batch[m] < gi) lo = m + 1; else hi = m; }
    int beg = lo;
    lo = beg; hi = N;
    while (lo < hi) { int m = (lo + hi) >> 1; if (batch[m] < gi + 1) lo = m + 1; else hi = m; }
    int end = lo;

    int tid = threadIdx.x;
    int wave = tid >> 6, lane = tid & 63;
    float2 acc = make_float2(0.f, 0.f);
    for (int r = beg + wave; r < end; r += 4) {
        unsigned int u = x[(size_t)r * 64 + lane];
        acc.x += b2f((unsigned short)(u & 0xFFFF));
        acc.y += b2f((unsigned short)(u >> 16));
    }
    __shared__ float part[4][DD];
    ((float2*)part[wave])[lane] = acc;
    __syncthreads();
    if (wave == 0) {
        float sx = 0.f, sy = 0.f;
#pragma unroll
        for (int w = 0; w < 4; ++w) {
            float2 v = ((const float2*)part[w])[lane];
            sx += v.x;
            sy += v.y;
        }
        float inv = 1.0f / fmaxf((float)(end - beg), 1.0f);
        ((float2*)(out + (size_t)gi * DD))[lane] = make_float2(sx * inv, sy * inv);
    }
}

extern "C" void kernel_launch(void* const* d_in, const int* in_sizes, int n_in,
                              void* d_out, int out_size, void* d_ws, size_t ws_size,
                              hipStream_t stream) {
    const float* x = (const float*)d_in[0];
    const int* edge = (const int*)d_in[1];
    const int* batch = (const int*)d_in[2];
    const float* W[3] = {(const float*)d_in[3], (const float*)d_in[7], (const float*)d_in[11]};
    const float* b[3] = {(const float*)d_in[4], (const float*)d_in[8], (const float*)d_in[12]};
    const float* g[3] = {(const float*)d_in[5], (const float*)d_in[9], (const float*)d_in[13]};
    const float* be[3] = {(const float*)d_in[6], (const float*)d_in[10], (const float*)d_in[14]};

    int N = in_sizes[0] / DD;
    int E = in_sizes[1] / 2;
    int G = out_size / DD;
    const int* srcI = edge;
    const int* dstI = edge + E;

    int nblk = (N + 255) / 256;

    char* ws = (char*)d_ws;
    size_t ND = (size_t)N * DD;
    unsigned int* bufX = (unsigned int*)ws;           ws += ND * 2;   // x state, bf16
    unsigned short* bufH = (unsigned short*)ws;       ws += ND * 2;   // hs = dinv*h, bf16
    unsigned short* wt[3];
    for (int l = 0; l < 3; ++l) { wt[l] = (unsigned short*)ws; ws += (size_t)DD * DD * 2; }
    float* dinv = (float*)ws;                         ws += (size_t)N * 4;
    int* cnt = (int*)ws;                              ws += (size_t)N * 4;
    int* rowptr = (int*)ws;                           ws += (size_t)(N + 1) * 4;
    int* part = (int*)ws;                             ws += (size_t)nblk * 4;
    ws = (char*)(((uintptr_t)ws + 15) & ~(uintptr_t)15);
    int* rank = (int*)ws;                             ws += (size_t)E * 4;
    int* adjS = (int*)ws;

    hipMemsetAsync(cnt, 0, (size_t)N * 4, stream);

    int histblk = (E + 1023) / 1024;
    k_setup<<<192 + histblk, 256, 0, stream>>>(dstI, cnt, rank, E, W[0], W[1], W[2], wt[0], wt[1], wt[2]);
    k_scan1<<<nblk, 256, 0, stream>>>(cnt, part, N);
    k_scan3<<<nblk, 256, 0, stream>>>(cnt, part, rowptr, dinv, N, nblk);

    int gblk = (N + 127) / 128, ablk = (N + 3) / 4;
    int fillblk = (E / 4 + 255) / 256 + 1;
    // layer 0: fp32 input; atomic-free scatter fused into the same launch
    k_gemm_mfma<0><<<gblk + fillblk, 256, 0, stream>>>(x, wt[0], dinv, bufH, N, gblk,
                                                       srcI, dstI, rank, rowptr, adjS, E);
    k_agg<0><<<ablk, 256, 0, stream>>>(bufH, x, rowptr, adjS, dinv, b[0], g[0], be[0], bufX, N);
    // layers 1,2: bf16 state (in-place safe: each thread reads own row before writing)
    for (int l = 1; l < 3; ++l) {
        k_gemm_mfma<1><<<gblk, 256, 0, stream>>>(bufX, wt[l], dinv, bufH, N, gblk,
                                                 srcI, dstI, rank, rowptr, adjS, E);
        k_agg<1><<<ablk, 256, 0, stream>>>(bufH, bufX, rowptr, adjS, dinv, b[l], g[l], be[l], bufX, N);
    }

    k_pool2<<<G, 256, 0, stream>>>(bufX, batch, (float*)d_out, N);
}

// Round 20
// 227.762 us; speedup vs baseline: 1.2332x; 1.0207x over previous
//
#include <hip/hip_runtime.h>
#include <math.h>

#define DD 128

typedef __attribute__((ext_vector_type(8))) short short8;
typedef __attribute__((ext_vector_type(4))) float f32x4;

__device__ __forceinline__ unsigned short f2b(float f) {
    unsigned int x = __float_as_uint(f);
    return (unsigned short)((x + 0x7FFFu + ((x >> 16) & 1u)) >> 16);   // RNE bf16
}
__device__ __forceinline__ float b2f(unsigned short u) {
    return __uint_as_float(((unsigned int)u) << 16);
}

// ---------------- fused setup: blocks [0,192) transpose W->bf16, rest histogram dst ----------------
// Histogram captures each edge's rank-within-dst from the atomic return value (round-19 win:
// the CSR fill then needs NO atomics).
__global__ __launch_bounds__(256) void k_setup(const int* __restrict__ dst, int* __restrict__ cnt,
                                               int* __restrict__ rank, int E,
                                               const float* __restrict__ W0, const float* __restrict__ W1,
                                               const float* __restrict__ W2, unsigned short* __restrict__ T0,
                                               unsigned short* __restrict__ T1, unsigned short* __restrict__ T2) {
    int bid = blockIdx.x;
    if (bid < 192) {
        int l = bid >> 6;
        const float* W = (l == 0) ? W0 : (l == 1) ? W1 : W2;
        unsigned short* WT = (l == 0) ? T0 : (l == 1) ? T1 : T2;
        int idx = (bid & 63) * 256 + threadIdx.x;   // 16384
        int k = idx >> 7, c = idx & 127;
        WT[c * DD + k] = f2b(W[idx]);
    } else {
        int base = ((bid - 192) * 256 + threadIdx.x) * 4;
        if (base + 3 < E) {
            int4 d4 = *(const int4*)(dst + base);
            int r0 = atomicAdd(&cnt[d4.x], 1);
            int r1 = atomicAdd(&cnt[d4.y], 1);
            int r2 = atomicAdd(&cnt[d4.z], 1);
            int r3 = atomicAdd(&cnt[d4.w], 1);
            *(int4*)(rank + base) = make_int4(r0, r1, r2, r3);
        } else {
            for (int e = base; e < E; ++e) rank[e] = atomicAdd(&cnt[dst[e]], 1);
        }
    }
}

// ---------------- scan phase 1: per-block sums ----------------
__global__ __launch_bounds__(256) void k_scan1(const int* __restrict__ cnt, int* __restrict__ part, int N) {
    __shared__ int lds[256];
    int t = threadIdx.x;
    int i = blockIdx.x * 256 + t;
    lds[t] = (i < N) ? cnt[i] : 0;
    __syncthreads();
#pragma unroll
    for (int off = 128; off > 0; off >>= 1) {
        if (t < off) lds[t] += lds[t + off];
        __syncthreads();
    }
    if (t == 0) part[blockIdx.x] = lds[0];
}

// ---------------- scan phase 2 (merged): every block scans the partials in LDS, then local scan ----------------
__global__ __launch_bounds__(256) void k_scan3(const int* __restrict__ cnt, const int* __restrict__ part,
                                               int* __restrict__ rowptr, float* __restrict__ dinv,
                                               int N, int nblk) {
    __shared__ int sp[256];
    __shared__ int lds[256];
    int t = threadIdx.x;
    sp[t] = (t < nblk) ? part[t] : 0;
    __syncthreads();
    for (int off = 1; off < 256; off <<= 1) {
        int u = (t >= off) ? sp[t - off] : 0;
        __syncthreads();
        sp[t] += u;
        __syncthreads();
    }
    int blockOff = (blockIdx.x > 0) ? sp[blockIdx.x - 1] : 0;

    int i = blockIdx.x * 256 + t;
    int v = (i < N) ? cnt[i] : 0;
    lds[t] = v;
    __syncthreads();
    for (int off = 1; off < 256; off <<= 1) {
        int u = (t >= off) ? lds[t - off] : 0;
        __syncthreads();
        lds[t] += u;
        __syncthreads();
    }
    if (i < N) {
        rowptr[i] = blockOff + lds[t] - v;
        dinv[i] = rsqrtf((float)v + 1.0f);
    }
    if (blockIdx.x == 0 && t == 0) rowptr[N] = sp[nblk - 1];   // = E
}

// ---------------- fused: layer GEMM (blocks < gblk) + atomic-free adjacency scatter ----------------
// A-operand read DIRECTLY from global (each A-fragment is consumed by exactly one wave and
// loaded once per K-step -> LDS staging of X was pure overhead; 32 KB LDS -> 4 blocks/CU).
template <int IN_BF16>
__global__ __launch_bounds__(256) void k_gemm_mfma(const void* __restrict__ Xv,
                                                   const unsigned short* __restrict__ WT,
                                                   const float* __restrict__ dinv,
                                                   unsigned short* __restrict__ H, int N, int gblk,
                                                   const int* __restrict__ src, const int* __restrict__ dst,
                                                   const int* __restrict__ rank,
                                                   const int* __restrict__ rowptr,
                                                   int* __restrict__ adjS, int E) {
    __shared__ __align__(16) unsigned short sB[DD * DD];    // WT swizzled, 32 KB
    int tid = threadIdx.x;

    if ((int)blockIdx.x >= gblk) {   // ---- scatter part (block-uniform branch, no LDS, no sync) ----
        int base = (((int)blockIdx.x - gblk) * 256 + tid) * 4;
        if (base + 3 < E) {
            int4 s4 = *(const int4*)(src + base);
            int4 d4 = *(const int4*)(dst + base);
            int4 r4 = *(const int4*)(rank + base);
            adjS[rowptr[d4.x] + r4.x] = s4.x;
            adjS[rowptr[d4.y] + r4.y] = s4.y;
            adjS[rowptr[d4.z] + r4.z] = s4.z;
            adjS[rowptr[d4.w] + r4.w] = s4.w;
        } else {
            for (int e = base; e < E && e >= 0; ++e)
                adjS[rowptr[dst[e]] + rank[e]] = src[e];
        }
        return;
    }

    long row0 = (long)blockIdx.x * 128;

#pragma unroll
    for (int i = 0; i < 8; ++i) {
        int q = tid + 256 * i;
        int c = q >> 4, j = q & 15;
        short8 v = *(const short8*)(WT + q * 8);
        int byte = c * 256 + ((j * 16) ^ ((c & 7) << 4));
        *(short8*)((char*)sB + byte) = v;
    }
    __syncthreads();

    int w = tid >> 6, l = tid & 63;
    int lr = l & 15, kg = l >> 4;
    long ar0 = row0 + w * 32 + lr, ar1 = ar0 + 16;
    f32x4 acc0[8] = {}, acc1[8] = {};

#pragma unroll
    for (int step = 0; step < 4; ++step) {
        int koff = step * 64 + kg * 16;        // byte offset within sB row (256B)
        int eoff = step * 32 + kg * 8;         // element offset within X row (128)
        short8 a0 = {}, a1 = {};
        if (IN_BF16) {
            if (ar0 < N) a0 = *(const short8*)((const unsigned short*)Xv + ar0 * DD + eoff);
            if (ar1 < N) a1 = *(const short8*)((const unsigned short*)Xv + ar1 * DD + eoff);
        } else {
            if (ar0 < N) {
                const float4* p = (const float4*)((const float*)Xv + ar0 * DD + eoff);
                float4 f0 = p[0], f1 = p[1];
                a0[0] = (short)f2b(f0.x); a0[1] = (short)f2b(f0.y);
                a0[2] = (short)f2b(f0.z); a0[3] = (short)f2b(f0.w);
                a0[4] = (short)f2b(f1.x); a0[5] = (short)f2b(f1.y);
                a0[6] = (short)f2b(f1.z); a0[7] = (short)f2b(f1.w);
            }
            if (ar1 < N) {
                const float4* p = (const float4*)((const float*)Xv + ar1 * DD + eoff);
                float4 f0 = p[0], f1 = p[1];
                a1[0] = (short)f2b(f0.x); a1[1] = (short)f2b(f0.y);
                a1[2] = (short)f2b(f0.z); a1[3] = (short)f2b(f0.w);
                a1[4] = (short)f2b(f1.x); a1[5] = (short)f2b(f1.y);
                a1[6] = (short)f2b(f1.z); a1[7] = (short)f2b(f1.w);
            }
        }
#pragma unroll
        for (int ct = 0; ct < 8; ++ct) {
            int c = ct * 16 + lr;
            short8 bf = *(const short8*)((const char*)sB + c * 256 + (koff ^ ((c & 7) << 4)));
            acc0[ct] = __builtin_amdgcn_mfma_f32_16x16x32_bf16(a0, bf, acc0[ct], 0, 0, 0);
            acc1[ct] = __builtin_amdgcn_mfma_f32_16x16x32_bf16(a1, bf, acc1[ct], 0, 0, 0);
        }
    }

    // dinv prescale: HS[r] = dinv[r] * h[r]
    float dv0[4], dv1[4];
#pragma unroll
    for (int reg = 0; reg < 4; ++reg) {
        long r = row0 + w * 32 + kg * 4 + reg;
        dv0[reg] = (r < N) ? dinv[r] : 0.f;
        dv1[reg] = (r + 16 < N) ? dinv[r + 16] : 0.f;
    }
#pragma unroll
    for (int ct = 0; ct < 8; ++ct) {
#pragma unroll
        for (int reg = 0; reg < 4; ++reg) {
            long r = row0 + w * 32 + kg * 4 + reg;
            if (r < N) H[r * DD + ct * 16 + lr] = f2b(dv0[reg] * acc0[ct][reg]);
            long r2 = r + 16;
            if (r2 < N) H[r2 * DD + ct * 16 + lr] = f2b(dv1[reg] * acc1[ct][reg]);
        }
    }
}

// ------- fused: aggregate (hs bf16, 64-lane x 4B gather, uniform-index shfl) -> LN -> SiLU -------
template <int IN_BF16>
__global__ __launch_bounds__(256) void k_agg(const unsigned short* __restrict__ h, const void* __restrict__ xin,
                                             const int* __restrict__ rowptr, const int* __restrict__ adjS,
                                             const float* __restrict__ dinv, const float* __restrict__ b,
                                             const float* __restrict__ g, const float* __restrict__ be,
                                             unsigned int* __restrict__ xout, int N) {
    int row = blockIdx.x * 4 + (threadIdx.x >> 6);
    if (row >= N) return;
    int lane = threadIdx.x & 63;
    const unsigned int* hu = (const unsigned int*)h;

    float dv = dinv[row];
    unsigned int us = hu[(size_t)row * 64 + lane];
    float selfx = b2f((unsigned short)(us & 0xFFFF));
    float selfy = b2f((unsigned short)(us >> 16));
    float2 acc = make_float2(0.f, 0.f);

    int beg = rowptr[row], end = rowptr[row + 1];
    for (int j0 = beg; j0 < end; j0 += 64) {
        int myj = j0 + lane;
        int a = (myj < end) ? adjS[myj] : 0;
        int cnt = min(64, end - j0);
        int cntR = (cnt + 15) & ~15;
        for (int k0 = 0; k0 < cntR; k0 += 16) {
            unsigned int un[16];
#pragma unroll
            for (int u = 0; u < 16; ++u) {
                int s = __shfl(a, k0 + u, 64);
                un[u] = hu[(size_t)s * 64 + lane];
            }
#pragma unroll
            for (int u = 0; u < 16; ++u) {
                float m = (k0 + u < cnt) ? 1.0f : 0.0f;   // wave-uniform mask
                acc.x = fmaf(m, b2f((unsigned short)(un[u] & 0xFFFF)), acc.x);
                acc.y = fmaf(m, b2f((unsigned short)(un[u] >> 16)), acc.y);
            }
        }
    }

    float2 bv = ((const float2*)b)[lane];
    float ox = fmaf(dv, selfx + acc.x, bv.x);
    float oy = fmaf(dv, selfy + acc.y, bv.y);

    // LayerNorm over 128
    float ssum = ox + oy;
#pragma unroll
    for (int o = 32; o > 0; o >>= 1) ssum += __shfl_xor(ssum, o, 64);
    float mu = ssum * (1.0f / 128.0f);
    float dx0 = ox - mu, dx1 = oy - mu;
    float vs = dx0 * dx0 + dx1 * dx1;
#pragma unroll
    for (int o = 32; o > 0; o >>= 1) vs += __shfl_xor(vs, o, 64);
    float rstd = rsqrtf(vs * (1.0f / 128.0f) + 1e-5f);

    float2 gv = ((const float2*)g)[lane];
    float2 bev = ((const float2*)be)[lane];
    float2 xv;
    if (IN_BF16) {
        unsigned int xu = ((const unsigned int*)xin)[(size_t)row * 64 + lane];
        xv = make_float2(b2f((unsigned short)(xu & 0xFFFF)), b2f((unsigned short)(xu >> 16)));
    } else {
        xv = ((const float2*)xin)[(size_t)row * 64 + lane];
    }
    float a0 = fmaf(dx0 * rstd, gv.x, bev.x) + xv.x;
    float a1 = fmaf(dx1 * rstd, gv.y, bev.y) + xv.y;
    a0 = a0 / (1.0f + expf(-a0));
    a1 = a1 / (1.0f + expf(-a1));
    xout[(size_t)row * 64 + lane] = ((unsigned int)f2b(a1) << 16) | (unsigned int)f2b(a0);
}

// ------- pool: one block per graph (batch sorted -> contiguous ranges), x bf16 -------
__global__ __launch_bounds__(256) void k_pool2(const unsigned int* __restrict__ x, const int* __restrict__ batch,
                                               float* __restrict__ out, int N) {
    int gi = blockIdx.x;
    int lo = 0, hi = N;
    while (lo < hi) { int m = (lo + hi) >> 1; if (batch[m] < gi) lo = m + 1; else hi = m; }
    int beg = lo;
    lo = beg; hi = N;
    while (lo < hi) { int m = (lo + hi) >> 1; if (batch[m] < gi + 1) lo = m + 1; else hi = m; }
    int end = lo;

    int tid = threadIdx.x;
    int wave = tid >> 6, lane = tid & 63;
    float2 acc = make_float2(0.f, 0.f);
    for (int r = beg + wave; r < end; r += 4) {
        unsigned int u = x[(size_t)r * 64 + lane];
        acc.x += b2f((unsigned short)(u & 0xFFFF));
        acc.y += b2f((unsigned short)(u >> 16));
    }
    __shared__ float part[4][DD];
    ((float2*)part[wave])[lane] = acc;
    __syncthreads();
    if (wave == 0) {
        float sx = 0.f, sy = 0.f;
#pragma unroll
        for (int w = 0; w < 4; ++w) {
            float2 v = ((const float2*)part[w])[lane];
            sx += v.x;
            sy += v.y;
        }
        float inv = 1.0f / fmaxf((float)(end - beg), 1.0f);
        ((float2*)(out + (size_t)gi * DD))[lane] = make_float2(sx * inv, sy * inv);
    }
}

extern "C" void kernel_launch(void* const* d_in, const int* in_sizes, int n_in,
                              void* d_out, int out_size, void* d_ws, size_t ws_size,
                              hipStream_t stream) {
    const float* x = (const float*)d_in[0];
    const int* edge = (const int*)d_in[1];
    const int* batch = (const int*)d_in[2];
    const float* W[3] = {(const float*)d_in[3], (const float*)d_in[7], (const float*)d_in[11]};
    const float* b[3] = {(const float*)d_in[4], (const float*)d_in[8], (const float*)d_in[12]};
    const float* g[3] = {(const float*)d_in[5], (const float*)d_in[9], (const float*)d_in[13]};
    const float* be[3] = {(const float*)d_in[6], (const float*)d_in[10], (const float*)d_in[14]};

    int N = in_sizes[0] / DD;
    int E = in_sizes[1] / 2;
    int G = out_size / DD;
    const int* srcI = edge;
    const int* dstI = edge + E;

    int nblk = (N + 255) / 256;

    char* ws = (char*)d_ws;
    size_t ND = (size_t)N * DD;
    unsigned int* bufX = (unsigned int*)ws;           ws += ND * 2;   // x state, bf16
    unsigned short* bufH = (unsigned short*)ws;       ws += ND * 2;   // hs = dinv*h, bf16
    unsigned short* wt[3];
    for (int l = 0; l < 3; ++l) { wt[l] = (unsigned short*)ws; ws += (size_t)DD * DD * 2; }
    float* dinv = (float*)ws;                         ws += (size_t)N * 4;
    int* cnt = (int*)ws;                              ws += (size_t)N * 4;
    int* rowptr = (int*)ws;                           ws += (size_t)(N + 1) * 4;
    int* part = (int*)ws;                             ws += (size_t)nblk * 4;
    ws = (char*)(((uintptr_t)ws + 15) & ~(uintptr_t)15);
    int* rank = (int*)ws;                             ws += (size_t)E * 4;
    int* adjS = (int*)ws;

    hipMemsetAsync(cnt, 0, (size_t)N * 4, stream);

    int histblk = (E + 1023) / 1024;
    k_setup<<<192 + histblk, 256, 0, stream>>>(dstI, cnt, rank, E, W[0], W[1], W[2], wt[0], wt[1], wt[2]);
    k_scan1<<<nblk, 256, 0, stream>>>(cnt, part, N);
    k_scan3<<<nblk, 256, 0, stream>>>(cnt, part, rowptr, dinv, N, nblk);

    int gblk = (N + 127) / 128, ablk = (N + 3) / 4;
    int fillblk = (E / 4 + 255) / 256 + 1;
    // layer 0: fp32 input; atomic-free scatter fused into the same launch
    k_gemm_mfma<0><<<gblk + fillblk, 256, 0, stream>>>(x, wt[0], dinv, bufH, N, gblk,
                                                       srcI, dstI, rank, rowptr, adjS, E);
    k_agg<0><<<ablk, 256, 0, stream>>>(bufH, x, rowptr, adjS, dinv, b[0], g[0], be[0], bufX, N);
    // layers 1,2: bf16 state (in-place safe: each thread reads own row before writing)
    for (int l = 1; l < 3; ++l) {
        k_gemm_mfma<1><<<gblk, 256, 0, stream>>>(bufX, wt[l], dinv, bufH, N, gblk,
                                                 srcI, dstI, rank, rowptr, adjS, E);
        k_agg<1><<<ablk, 256, 0, stream>>>(bufH, bufX, rowptr, adjS, dinv, b[l], g[l], be[l], bufX, N);
    }

    k_pool2<<<G, 256, 0, stream>>>(bufX, batch, (float*)d_out, N);
}